// Round 2
// baseline (444.674 us; speedup 1.0000x reference)
//
#include <hip/hip_runtime.h>
#include <stdint.h>

#define S_LEN 2048
#define HEADS 16
#define DIM   64
// bh = b*HEADS + h, BH = 32. S*D = 1<<17. H*S*D = 1<<21.

typedef float  f4v  __attribute__((ext_vector_type(4)));
typedef float  f2v  __attribute__((ext_vector_type(2)));
typedef float  f16v __attribute__((ext_vector_type(16)));
typedef short  s8v  __attribute__((ext_vector_type(8)));
typedef unsigned int   u4v  __attribute__((ext_vector_type(4)));
typedef unsigned short us4v __attribute__((ext_vector_type(4)));

__device__ __forceinline__ unsigned short f2bf(float f) {
  unsigned int u = __float_as_uint(f);
  u += 0x7fffu + ((u >> 16) & 1u);   // round-to-nearest-even
  return (unsigned short)(u >> 16);
}
__device__ __forceinline__ float bf2f(unsigned short h) {
  return __uint_as_float(((unsigned int)h) << 16);
}
__device__ __forceinline__ unsigned int pk2(float e0, float e1) {
  return (unsigned int)f2bf(e0) | ((unsigned int)f2bf(e1) << 16);
}

// ---- prep: K [B,S,H,D] f32 -> Khi/Klo [B,H,S,D] bf16 (hi/lo split) ----
__global__ __launch_bounds__(256) void prep_k(const float* __restrict__ K,
                                              unsigned short* __restrict__ Khi,
                                              unsigned short* __restrict__ Klo) {
  int idx = blockIdx.x * 256 + threadIdx.x;       // 2^20 threads
  size_t f = (size_t)idx * 4;                     // dst flat index [B,H,S,D]
  int d  = (int)(f & 63);
  int s  = (int)((f >> 6) & 2047);
  int hh = (int)((f >> 17) & 15);
  int b  = (int)(f >> 21);
  const float* src = K + (((size_t)(b * S_LEN + s) * HEADS + hh) << 6) + d;
  f4v v = *(const f4v*)src;
  us4v hi, lo;
#pragma unroll
  for (int i = 0; i < 4; ++i) {
    unsigned short h = f2bf(v[i]);
    hi[i] = h;
    lo[i] = f2bf(v[i] - bf2f(h));
  }
  *(us4v*)(Khi + f) = hi;
  *(us4v*)(Klo + f) = lo;
}

// ---- prep: V [B,S,H,D] f32 -> Vt [B,H,D,S] bf16 (transpose + convert) ----
__global__ __launch_bounds__(256) void prep_v(const float* __restrict__ V,
                                              unsigned short* __restrict__ Vt) {
  int bh = blockIdx.x >> 5;
  int s0 = (blockIdx.x & 31) * 64;
  int b = bh >> 4, hh = bh & 15;
  int t = threadIdx.x;
  int sg = t & 15, dg = t >> 4;                   // 4x4 block per thread
  const float* base =
      V + (((size_t)(b * S_LEN + s0 + 4 * sg) * HEADS + hh) << 6) + 4 * dg;
  f4v r[4];
#pragma unroll
  for (int i = 0; i < 4; ++i) r[i] = *(const f4v*)(base + (size_t)i * (HEADS * DIM));
#pragma unroll
  for (int i2 = 0; i2 < 4; ++i2) {
    us4v w;
#pragma unroll
    for (int j = 0; j < 4; ++j) w[j] = f2bf(r[j][i2]);
    *(us4v*)(Vt + ((size_t)bh * DIM + 4 * dg + i2) * S_LEN + s0 + 4 * sg) = w;
  }
}

// ---- main: flash attention, 1 wave = 32 q rows, no LDS, no barriers ----
// PARTIAL=1: process NT kv-tiles from kv_begin, write unnormalized O + (m,l).
// PARTIAL=0: full S sweep, write normalized output directly.
template <int PARTIAL>
__global__ __launch_bounds__(256, 4) void attn_fwd(
    const float* __restrict__ Q, const float* __restrict__ MASK,
    const float* __restrict__ U, const unsigned short* __restrict__ Khi,
    const unsigned short* __restrict__ Klo, const unsigned short* __restrict__ Vt,
    float* __restrict__ OUT, float* __restrict__ OPART, float* __restrict__ ML) {
  int bid = blockIdx.x;
  int bh, qt, sp;
  if (PARTIAL) {
    // 1024 blocks: XCD-bijective swizzle, 128 blocks/XCD -> 4 bh per XCD
    int lid = ((bid & 7) << 7) + (bid >> 3);
    bh = lid >> 5;
    qt = (lid >> 1) & 15;
    sp = lid & 1;
  } else {
    int lid = ((bid & 7) << 6) + (bid >> 3);      // 512 blocks
    bh = lid >> 4;
    qt = lid & 15;
    sp = 0;
  }
  const int NT = PARTIAL ? (S_LEN / 64) : (S_LEN / 32);
  const int kv_begin = PARTIAL ? sp * (S_LEN / 2) : 0;

  int wv = threadIdx.x >> 6, ln = threadIdx.x & 63;
  int l31 = ln & 31, h5 = ln >> 5;
  int q = qt * 128 + wv * 32 + l31;
  int b = bh >> 4, hh = bh & 15;

  // Q B-fragments (hi/lo): B[n=q=lane&31][k=d = dc*16 + 8*h5 + j]
  const float* qrow = Q + (((size_t)(b * S_LEN + q) * HEADS + hh) << 6);
  s8v qfh[4], qfl[4];
#pragma unroll
  for (int dc = 0; dc < 4; ++dc) {
    const float* p = qrow + dc * 16 + 8 * h5;
    f4v va = *(const f4v*)p;
    f4v vb = *(const f4v*)(p + 4);
    u4v wh, wl;
#pragma unroll
    for (int t = 0; t < 4; ++t) {
      float x0 = (t < 2) ? va[2 * t] : vb[2 * (t - 2)];
      float x1 = (t < 2) ? va[2 * t + 1] : vb[2 * (t - 2) + 1];
      unsigned short h0 = f2bf(x0), h1 = f2bf(x1);
      wh[t] = (unsigned)h0 | ((unsigned)h1 << 16);
      wl[t] = pk2(x0 - bf2f(h0), x1 - bf2f(h1));
    }
    qfh[dc] = __builtin_bit_cast(s8v, wh);
    qfl[dc] = __builtin_bit_cast(s8v, wl);
  }

  const size_t mb = ((size_t)bh * S_LEN + q) * S_LEN;
  const float* mrow = MASK + mb + kv_begin;
  const float* urow = U + mb + kv_begin;
  const unsigned short* kbh = Khi + ((size_t)bh << 17) + ((size_t)kv_begin << 6);
  const unsigned short* kbl = Klo + ((size_t)bh << 17) + ((size_t)kv_begin << 6);
  const unsigned short* vbp = Vt + ((size_t)bh << 17) + kv_begin;

  f16v o0, o1;
#pragma unroll
  for (int i = 0; i < 16; ++i) { o0[i] = 0.f; o1[i] = 0.f; }
  float mrun = -3.0e38f, lsum = 0.f;

  for (int kt = 0; kt < NT; ++kt) {
    int kv0 = kt << 5;
    // K A-fragments: A[m=kv=lane&31][k=d]
    s8v kfh[4], kfl[4];
#pragma unroll
    for (int dc = 0; dc < 4; ++dc) {
      size_t off = ((size_t)(kv0 + l31) << 6) + dc * 16 + 8 * h5;
      kfh[dc] = *(const s8v*)(kbh + off);
      kfl[dc] = *(const s8v*)(kbl + off);
    }
    // V^T A-fragments: A[m=d=lane&31 (+32)][k=kv]
    s8v vf0[2], vf1[2];
#pragma unroll
    for (int kc = 0; kc < 2; ++kc) {
      size_t o_ = ((size_t)l31 << 11) + (size_t)(kv0 + kc * 16 + 8 * h5);
      vf0[kc] = *(const s8v*)(vbp + o_);
      vf1[kc] = *(const s8v*)(vbp + ((size_t)32 << 11) + o_);
    }
    // mask / dropout fragments in S^T C-layout: k = kv0 + 8g + 4*h5 + i
    f4v mk[4], uk[4];
#pragma unroll
    for (int g = 0; g < 4; ++g) {
      int ko = kv0 + 8 * g + 4 * h5;
      mk[g] = *(const f4v*)(mrow + ko);
      uk[g] = *(const f4v*)(urow + ko);
    }
    // S^T = K·Q^T, fp32-accurate via hi/lo split
    f16v sc;
#pragma unroll
    for (int i = 0; i < 16; ++i) sc[i] = 0.f;
#pragma unroll
    for (int dc = 0; dc < 4; ++dc) {
      sc = __builtin_amdgcn_mfma_f32_32x32x16_bf16(kfh[dc], qfh[dc], sc, 0, 0, 0);
      sc = __builtin_amdgcn_mfma_f32_32x32x16_bf16(kfh[dc], qfl[dc], sc, 0, 0, 0);
      sc = __builtin_amdgcn_mfma_f32_32x32x16_bf16(kfl[dc], qfh[dc], sc, 0, 0, 0);
    }
    // scale (ref: scores / INV_SCALE = *8) + mask; online softmax
    float sv[16];
    float pmax = -3.0e38f;
#pragma unroll
    for (int r = 0; r < 16; ++r) {
      sv[r] = sc[r] * 8.0f + mk[r >> 2][r & 3];
      pmax = fmaxf(pmax, sv[r]);
    }
    pmax = fmaxf(pmax, __shfl_xor(pmax, 32));
    float mn = fmaxf(mrun, pmax);
    float al = __expf(mrun - mn);
    mrun = mn;
    lsum *= al;
#pragma unroll
    for (int i = 0; i < 16; ++i) { o0[i] *= al; o1[i] *= al; }
    float pv[16];
#pragma unroll
    for (int r = 0; r < 16; ++r) {
      pv[r] = __expf(sv[r] - mn);
      lsum += pv[r];   // denominator WITHOUT dropout (per reference)
    }
    // dropout + pack to bf16 pairs (own k = 8g + 4*h5 + {0..3})
    unsigned a0[4], a1[4];
#pragma unroll
    for (int g = 0; g < 4; ++g) {
      float d0 = (uk[g][0] >= 0.1f) ? pv[4 * g + 0] * (1.0f / 0.9f) : 0.f;
      float d1 = (uk[g][1] >= 0.1f) ? pv[4 * g + 1] * (1.0f / 0.9f) : 0.f;
      float d2 = (uk[g][2] >= 0.1f) ? pv[4 * g + 2] * (1.0f / 0.9f) : 0.f;
      float d3 = (uk[g][3] >= 0.1f) ? pv[4 * g + 3] * (1.0f / 0.9f) : 0.f;
      a0[g] = pk2(d0, d1);
      a1[g] = pk2(d2, d3);
    }
    // P^T B-fragments via half-wave exchange: B[k=kc*16+8*h5+j][n=q=lane&31]
    s8v pb[2];
#pragma unroll
    for (int kc = 0; kc < 2; ++kc) {
      unsigned x0 = a0[2 * kc], x1 = a0[2 * kc + 1];
      unsigned y0 = a1[2 * kc], y1 = a1[2 * kc + 1];
      unsigned sx0 = __shfl_xor(x0, 32), sx1 = __shfl_xor(x1, 32);
      unsigned sy0 = __shfl_xor(y0, 32), sy1 = __shfl_xor(y1, 32);
      u4v w;
      w[0] = h5 ? sx1 : x0;
      w[1] = h5 ? sy1 : y0;
      w[2] = h5 ? x1 : sx0;
      w[3] = h5 ? y1 : sy0;
      pb[kc] = __builtin_bit_cast(s8v, w);
    }
    // O^T += V^T · P^T
    o0 = __builtin_amdgcn_mfma_f32_32x32x16_bf16(vf0[0], pb[0], o0, 0, 0, 0);
    o0 = __builtin_amdgcn_mfma_f32_32x32x16_bf16(vf0[1], pb[1], o0, 0, 0, 0);
    o1 = __builtin_amdgcn_mfma_f32_32x32x16_bf16(vf1[0], pb[0], o1, 0, 0, 0);
    o1 = __builtin_amdgcn_mfma_f32_32x32x16_bf16(vf1[1], pb[1], o1, 0, 0, 0);
  }

  lsum += __shfl_xor(lsum, 32);
  // O^T C-layout: col = q = lane&31, row = d = 8g + 4*h5 + i (+32 for o1)
  if (PARTIAL) {
    size_t row = (size_t)bh * S_LEN + q;
    float* orow = OPART + row * 128 + sp * 64;    // unnormalized
#pragma unroll
    for (int df = 0; df < 2; ++df) {
#pragma unroll
      for (int g = 0; g < 4; ++g) {
        f4v w;
#pragma unroll
        for (int i = 0; i < 4; ++i) w[i] = df ? o1[4 * g + i] : o0[4 * g + i];
        *(f4v*)(orow + df * 32 + 8 * g + 4 * h5) = w;
      }
    }
    if (h5 == 0) {
      f2v s; s[0] = mrun; s[1] = lsum;
      *(f2v*)(ML + row * 4 + sp * 2) = s;
    }
  } else {
    float inv = 1.0f / lsum;
    float* orow = OUT + (((size_t)bh * S_LEN + q) << 6);
#pragma unroll
    for (int df = 0; df < 2; ++df) {
#pragma unroll
      for (int g = 0; g < 4; ++g) {
        f4v w;
#pragma unroll
        for (int i = 0; i < 4; ++i) w[i] = (df ? o1[4 * g + i] : o0[4 * g + i]) * inv;
        *(f4v*)(orow + df * 32 + 8 * g + 4 * h5) = w;
      }
    }
  }
}

// ---- combine: merge 2 kv-splits per q row ----
__global__ __launch_bounds__(256) void combine(const float* __restrict__ OPART,
                                               const float* __restrict__ ML,
                                               float* __restrict__ OUT) {
  int gid = blockIdx.x * 256 + threadIdx.x;       // 1M threads
  size_t row = (size_t)(gid >> 4);                // bh*2048 + q
  int d4 = (gid & 15) * 4;
  f4v mlv = *(const f4v*)(ML + row * 4);
  float m0 = mlv[0], l0 = mlv[1], m1 = mlv[2], l1 = mlv[3];
  float M = fmaxf(m0, m1);
  float w0 = __expf(m0 - M), w1 = __expf(m1 - M);
  float inv = 1.0f / (l0 * w0 + l1 * w1);
  f4v a = *(const f4v*)(OPART + row * 128 + d4);
  f4v bb = *(const f4v*)(OPART + row * 128 + 64 + d4);
  f4v o;
#pragma unroll
  for (int i = 0; i < 4; ++i) o[i] = (a[i] * w0 + bb[i] * w1) * inv;
  *(f4v*)(OUT + row * 64 + d4) = o;
}

extern "C" void kernel_launch(void* const* d_in, const int* in_sizes, int n_in,
                              void* d_out, int out_size, void* d_ws, size_t ws_size,
                              hipStream_t stream) {
  const float* Q = (const float*)d_in[0];
  const float* K = (const float*)d_in[1];
  const float* V = (const float*)d_in[2];
  const float* M = (const float*)d_in[3];
  const float* U = (const float*)d_in[4];
  float* out = (float*)d_out;

  unsigned short* Khi = (unsigned short*)d_ws;              // 8 MB
  unsigned short* Klo = Khi + (size_t)(4u << 20);           // 8 MB
  unsigned short* Vt  = Klo + (size_t)(4u << 20);           // 8 MB
  float* Opart = (float*)(Vt + (size_t)(4u << 20));         // 32 MB (65536*128 f32)
  float* ML    = Opart + (size_t)65536 * 128;               // 1 MB  (65536*4 f32)
  const size_t need = (size_t)(3 * 8 + 32 + 1) * 1024 * 1024 + (1u << 20);

  prep_k<<<4096, 256, 0, stream>>>(K, Khi, Klo);
  prep_v<<<1024, 256, 0, stream>>>(V, Vt);
  if (ws_size >= need) {
    attn_fwd<1><<<1024, 256, 0, stream>>>(Q, M, U, Khi, Klo, Vt, out, Opart, ML);
    combine<<<4096, 256, 0, stream>>>(Opart, ML, out);
  } else {
    attn_fwd<0><<<512, 256, 0, stream>>>(Q, M, U, Khi, Klo, Vt, out, Opart, ML);
  }
}

// Round 4
// 310.127 us; speedup vs baseline: 1.4338x; 1.4338x over previous
//
#include <hip/hip_runtime.h>
#include <stdint.h>

#define S_LEN 2048
#define HEADS 16
#define DIM   64
// bh = b*HEADS + h, BH = 32.

typedef float  f4v  __attribute__((ext_vector_type(4)));
typedef float  f16v __attribute__((ext_vector_type(16)));
typedef short  s8v  __attribute__((ext_vector_type(8)));
typedef unsigned int   u4v  __attribute__((ext_vector_type(4)));
typedef unsigned short us4v __attribute__((ext_vector_type(4)));

__device__ __forceinline__ unsigned short f2bf(float f) {
  unsigned int u = __float_as_uint(f);
  u += 0x7fffu + ((u >> 16) & 1u);   // round-to-nearest-even
  return (unsigned short)(u >> 16);
}
__device__ __forceinline__ float bf2f(unsigned short h) {
  return __uint_as_float(((unsigned int)h) << 16);
}
__device__ __forceinline__ unsigned int pk2(float e0, float e1) {
  return (unsigned int)f2bf(e0) | ((unsigned int)f2bf(e1) << 16);
}

// ---- prep: K [B,S,H,D] f32 -> fragment-ordered bf16 hi/lo ----
// Khf/Klf flat: [bh][kt][dc][lane][j=8] ; value = K(s=kt*32+(l&31), d=dc*16+(l>>5)*8+j)
__global__ __launch_bounds__(256) void prep_k(const float* __restrict__ K,
                                              unsigned short* __restrict__ Khf,
                                              unsigned short* __restrict__ Klf) {
  int f = blockIdx.x * 256 + threadIdx.x;          // 2048 blocks -> 524288 threads
  int l  = f & 63;
  int dc = (f >> 6) & 3;
  int kt = (f >> 8) & 63;
  int bh = f >> 14;
  int b = bh >> 4, hh = bh & 15;
  int s  = kt * 32 + (l & 31);
  int d0 = dc * 16 + (l >> 5) * 8;
  const float* src = K + (((size_t)(b * S_LEN + s) * HEADS + hh) << 6) + d0;
  f4v va = *(const f4v*)src;
  f4v vb = *(const f4v*)(src + 4);
  us4v ha, hb, la, lb;
#pragma unroll
  for (int i = 0; i < 4; ++i) {
    unsigned short h = f2bf(va[i]);
    ha[i] = h; la[i] = f2bf(va[i] - bf2f(h));
    unsigned short h2 = f2bf(vb[i]);
    hb[i] = h2; lb[i] = f2bf(vb[i] - bf2f(h2));
  }
  size_t o = (size_t)f * 8;
  *(us4v*)(Khf + o) = ha; *(us4v*)(Khf + o + 4) = hb;
  *(us4v*)(Klf + o) = la; *(us4v*)(Klf + o + 4) = lb;
}

// ---- prep: V [B,S,H,D] f32 -> fragment-ordered bf16 via LDS tile ----
// Vf flat: [bh][kt][kc*2+dblk][lane][j=8] ; value = V(s=kt*32+kc*16+(l>>5)*8+j, d=dblk*32+(l&31))
__global__ __launch_bounds__(256) void prep_v(const float* __restrict__ V,
                                              unsigned short* __restrict__ Vf) {
  __shared__ float tile[32 * 68];                  // pitch 68 floats
  int bh = blockIdx.x >> 6;
  int kt = blockIdx.x & 63;
  int b = bh >> 4, hh = bh & 15;
  int t = threadIdx.x;
  {
    int row = t >> 3, c8 = (t & 7) * 8;
    const float* src =
        V + (((size_t)(b * S_LEN + kt * 32 + row) * HEADS + hh) << 6) + c8;
    f4v va = *(const f4v*)src;
    f4v vb = *(const f4v*)(src + 4);
    *(f4v*)(tile + row * 68 + c8) = va;
    *(f4v*)(tile + row * 68 + c8 + 4) = vb;
  }
  __syncthreads();
  int kc = t >> 7, dblk = (t >> 6) & 1, l = t & 63;
  int s0 = kc * 16 + (l >> 5) * 8;
  int col = dblk * 32 + (l & 31);
  us4v w0, w1;
#pragma unroll
  for (int j = 0; j < 4; ++j) {
    w0[j] = f2bf(tile[(s0 + j) * 68 + col]);
    w1[j] = f2bf(tile[(s0 + 4 + j) * 68 + col]);
  }
  size_t o = ((((size_t)bh * 64 + kt) * 4 + kc * 2 + dblk) * 64 + l) * 8;
  *(us4v*)(Vf + o) = w0;
  *(us4v*)(Vf + o + 4) = w1;
}

// ---- main: flash attention, normal-orientation S, coalesced mask/u,
//      exact per-row online softmax (butterfly row-max) ----
__global__ __launch_bounds__(256, 2) void attn_fwd(
    const float* __restrict__ Q, const float* __restrict__ MASK,
    const float* __restrict__ U, const unsigned short* __restrict__ Khf,
    const unsigned short* __restrict__ Klf, const unsigned short* __restrict__ Vf,
    float* __restrict__ OUT) {
  __shared__ short P_lds[4][2048];                 // per-wave 32x64 shorts
  int bid = blockIdx.x;
  int lid = ((bid & 7) << 6) + (bid >> 3);         // XCD-bijective swizzle (512)
  int bh = lid >> 4, qt = lid & 15;
  int wv = threadIdx.x >> 6, ln = threadIdx.x & 63;
  int l31 = ln & 31, h5 = ln >> 5;
  int q0 = qt * 128 + wv * 32;
  int b = bh >> 4, hh = bh & 15;
  short* lds = &P_lds[wv][0];

  // Q A-fragments (hi/lo): lane l -> row q0+l31, d = dc*16 + 8*h5 + j
  const float* qrow = Q + (((size_t)(b * S_LEN + q0 + l31) * HEADS + hh) << 6);
  s8v qfh[4], qfl[4];
#pragma unroll
  for (int dc = 0; dc < 4; ++dc) {
    const float* p = qrow + dc * 16 + 8 * h5;
    f4v va = *(const f4v*)p;
    f4v vb = *(const f4v*)(p + 4);
    u4v wh, wl;
#pragma unroll
    for (int t = 0; t < 4; ++t) {
      float x0 = (t < 2) ? va[2 * t] : vb[2 * (t - 2)];
      float x1 = (t < 2) ? va[2 * t + 1] : vb[2 * (t - 2) + 1];
      unsigned short h0 = f2bf(x0), h1 = f2bf(x1);
      wh[t] = (unsigned)h0 | ((unsigned)h1 << 16);
      wl[t] = pk2(x0 - bf2f(h0), x1 - bf2f(h1));
    }
    qfh[dc] = __builtin_bit_cast(s8v, wh);
    qfl[dc] = __builtin_bit_cast(s8v, wl);
  }

  const float* Mp = MASK + ((size_t)bh << 22);
  const float* Up = U + ((size_t)bh << 22);
  const int vbase = (q0 + 4 * h5) * S_LEN + l31;
  const unsigned short* kbh = Khf + ((size_t)bh << 17);
  const unsigned short* kbl = Klf + ((size_t)bh << 17);
  const unsigned short* vbp = Vf + ((size_t)bh << 17);
  const int fl8 = ln * 8;
  // transposed-side (lane=row) mapping: row l31 lives in reg rq of half h5p
  const int rq  = (l31 & 3) | (((l31 >> 3) & 3) << 2);
  const int h5p = (l31 >> 2) & 1;

  f16v o0, o1;
#pragma unroll
  for (int i = 0; i < 16; ++i) { o0[i] = 0.f; o1[i] = 0.f; }
  float mrun[16];
#pragma unroll
  for (int i = 0; i < 16; ++i) mrun[i] = -3.0e38f;
  float plane = 0.f;

  for (int kt = 0; kt < S_LEN / 32; ++kt) {
    int kv0 = kt << 5;
    // K B-fragments (coalesced 1KB loads)
    s8v kfh[4], kfl[4];
#pragma unroll
    for (int dc = 0; dc < 4; ++dc) {
      size_t off = (size_t)((kt * 4 + dc) << 9) + fl8;
      kfh[dc] = *(const s8v*)(kbh + off);
      kfl[dc] = *(const s8v*)(kbl + off);
    }
    // V B-fragments (coalesced 1KB loads)
    s8v vf[2][2];
#pragma unroll
    for (int kc = 0; kc < 2; ++kc)
#pragma unroll
      for (int db = 0; db < 2; ++db)
        vf[kc][db] = *(const s8v*)(vbp + (size_t)((kt * 4 + kc * 2 + db) << 9) + fl8);
    // mask / u in C-layout: reg r -> row q0+8*(r>>2)+4*h5+(r&3), col kv0+l31 (coalesced)
    float mk[16], uk[16];
#pragma unroll
    for (int r = 0; r < 16; ++r) {
      int off = vbase + kv0 + (8 * (r >> 2) + (r & 3)) * S_LEN;
      mk[r] = Mp[off];
      uk[r] = Up[off];
    }
    // S = Q·K^T (fp32-accurate via hi/lo split)
    f16v sc;
#pragma unroll
    for (int i = 0; i < 16; ++i) sc[i] = 0.f;
#pragma unroll
    for (int dc = 0; dc < 4; ++dc) {
      sc = __builtin_amdgcn_mfma_f32_32x32x16_bf16(qfh[dc], kfh[dc], sc, 0, 0, 0);
      sc = __builtin_amdgcn_mfma_f32_32x32x16_bf16(qfl[dc], kfh[dc], sc, 0, 0, 0);
      sc = __builtin_amdgcn_mfma_f32_32x32x16_bf16(qfh[dc], kfl[dc], sc, 0, 0, 0);
    }
    // scores + exact per-row tile max (5-step butterfly within each 32-lane half)
    float sv[16], tmax[16];
#pragma unroll
    for (int r = 0; r < 16; ++r) {
      sv[r] = fmaf(sc[r], 8.0f, mk[r]);
      tmax[r] = sv[r];
    }
#pragma unroll
    for (int d = 1; d < 32; d <<= 1)
#pragma unroll
      for (int r = 0; r < 16; ++r)
        tmax[r] = fmaxf(tmax[r], __shfl_xor(tmax[r], d));
    // defer-max (THR=8), wave-uniform trigger, per-row rescale
    bool grow = false;
#pragma unroll
    for (int r = 0; r < 16; ++r) grow |= (tmax[r] > mrun[r] + 8.0f);
    if (__any(grow)) {
      float alr[16];
#pragma unroll
      for (int r = 0; r < 16; ++r) {
        float mn = fmaxf(mrun[r], tmax[r]);
        alr[r] = __expf(mrun[r] - mn);
        mrun[r] = mn;
      }
#pragma unroll
      for (int i = 0; i < 16; ++i) { o0[i] *= alr[i]; o1[i] *= alr[i]; }
      // deliver row-l31's rescale factor to the transposed accumulator
      float x = alr[rq];
      float y = __shfl_xor(x, 32);
      plane *= (h5 == h5p) ? x : y;
    }
    // P' = exp(sv - mrun)/0.9 in bf16, sign bit = dropped; wave-private LDS [q][k]
#pragma unroll
    for (int r = 0; r < 16; ++r) {
      float pp = __expf(sv[r] - mrun[r]) * (1.0f / 0.9f);
      unsigned short bits = f2bf(pp);
      if (uk[r] < 0.1f) bits |= 0x8000;
      int qr = 8 * (r >> 2) + 4 * h5 + (r & 3);
      lds[qr * 64 + (((l31 >> 3) ^ (qr & 7)) << 3) + (l31 & 7)] = (short)bits;
    }
    __builtin_amdgcn_sched_barrier(0);             // forbid read-before-write reorder
    // read P A-fragments (swizzled, conflict-free): lane -> row l31, k chunk kc*16+h5*8
    s8v pa[2];
#pragma unroll
    for (int kc = 0; kc < 2; ++kc) {
      int blk = (2 * kc + h5) ^ (l31 & 7);
      u4v bits = *(u4v*)(lds + l31 * 64 + blk * 8);
      u4v absb, kept;
#pragma unroll
      for (int i = 0; i < 4; ++i) {
        absb[i] = bits[i] & 0x7FFF7FFFu;
        unsigned dropm = ((bits[i] >> 15) & 0x00010001u) * 0xFFFFu;
        kept[i] = absb[i] & ~dropm;
        plane += __uint_as_float((absb[i] & 0xFFFFu) << 16);
        plane += __uint_as_float(absb[i] & 0xFFFF0000u);
      }
      pa[kc] = __builtin_bit_cast(s8v, kept);
    }
    // O += P·V
    o0 = __builtin_amdgcn_mfma_f32_32x32x16_bf16(pa[0], vf[0][0], o0, 0, 0, 0);
    o0 = __builtin_amdgcn_mfma_f32_32x32x16_bf16(pa[1], vf[1][0], o0, 0, 0, 0);
    o1 = __builtin_amdgcn_mfma_f32_32x32x16_bf16(pa[0], vf[0][1], o1, 0, 0, 0);
    o1 = __builtin_amdgcn_mfma_f32_32x32x16_bf16(pa[1], vf[1][1], o1, 0, 0, 0);
  }

  // plane: lane holds undropped |P'| sum for row l31 (its k-half); combine halves
  plane += __shfl_xor(plane, 32);
  float inv = 1.0f / (0.9f * plane);
  float invv[16];
#pragma unroll
  for (int r = 0; r < 16; ++r)
    invv[r] = __shfl(inv, 8 * (r >> 2) + 4 * h5 + (r & 3));
  // store: row q0+qr, col d = db*32 + l31 (coalesced)
#pragma unroll
  for (int r = 0; r < 16; ++r) {
    int qr = 8 * (r >> 2) + 4 * h5 + (r & 3);
    float* orow = OUT + (((size_t)bh * S_LEN + q0 + qr) << 6) + l31;
    orow[0]  = o0[r] * invv[r];
    orow[32] = o1[r] * invv[r];
  }
}

extern "C" void kernel_launch(void* const* d_in, const int* in_sizes, int n_in,
                              void* d_out, int out_size, void* d_ws, size_t ws_size,
                              hipStream_t stream) {
  const float* Q = (const float*)d_in[0];
  const float* K = (const float*)d_in[1];
  const float* V = (const float*)d_in[2];
  const float* M = (const float*)d_in[3];
  const float* U = (const float*)d_in[4];
  float* out = (float*)d_out;

  unsigned short* Khf = (unsigned short*)d_ws;              // 8 MB
  unsigned short* Klf = Khf + (size_t)(4u << 20);           // 8 MB
  unsigned short* Vf  = Klf + (size_t)(4u << 20);           // 8 MB (total 24 MB)

  prep_k<<<2048, 256, 0, stream>>>(K, Khf, Klf);
  prep_v<<<2048, 256, 0, stream>>>(V, Vf);
  attn_fwd<<<512, 256, 0, stream>>>(Q, M, U, Khf, Klf, Vf, out);
}